// Round 4
// baseline (142.590 us; speedup 1.0000x reference)
//
#include <hip/hip_runtime.h>

#define N_TOTAL (8 * 128 * 128 * 128)   // 16,777,216 elements
#define THREADS 1024
#define BLOCKS  1024
#define STRIDE  (BLOCKS * THREADS)      // 1,048,576 -> 16 iterations/thread

__device__ __forceinline__ float svl_elem(float x, float t) {
    // BCEWithLogits (stable): max(x,0) - x*t + log1p(exp(-|x|))
    float loss = fmaxf(x, 0.0f) - x * t + __logf(1.0f + __expf(-fabsf(x)));
    // sigmoid(x) > 0.5  <=>  x > 0 ; weight = (pred XOR tgt) ? 1.5 : 1.0
    bool pred = x > 0.0f;
    bool tgt  = t > 0.5f;
    float w = (pred != tgt) ? 1.5f : 1.0f;
    return loss * w;
}

// Canonical BabelStream-dot structure: scalar loads, grid-stride, high occupancy.
__global__ __launch_bounds__(THREADS) void svl_partial_kernel(
        const float* __restrict__ yp, const float* __restrict__ yt,
        float* __restrict__ partial) {
    int idx = blockIdx.x * THREADS + threadIdx.x;

    float acc = 0.0f;
    for (int i = idx; i < N_TOTAL; i += STRIDE)
        acc += svl_elem(yp[i], yt[i]);

    // wave-64 shuffle reduction
    #pragma unroll
    for (int off = 32; off > 0; off >>= 1)
        acc += __shfl_down(acc, off, 64);

    __shared__ float smem[THREADS / 64];
    int lane = threadIdx.x & 63;
    int wave = threadIdx.x >> 6;
    if (lane == 0) smem[wave] = acc;
    __syncthreads();

    if (threadIdx.x == 0) {
        float s = 0.0f;
        #pragma unroll
        for (int w = 0; w < THREADS / 64; ++w) s += smem[w];
        partial[blockIdx.x] = s;
    }
}

__global__ __launch_bounds__(256) void svl_final_kernel(
        const float* __restrict__ partial, float* __restrict__ out) {
    float acc = 0.0f;
    for (int i = threadIdx.x; i < BLOCKS; i += 256)
        acc += partial[i];

    #pragma unroll
    for (int off = 32; off > 0; off >>= 1)
        acc += __shfl_down(acc, off, 64);

    __shared__ float smem[4];
    int lane = threadIdx.x & 63;
    int wave = threadIdx.x >> 6;
    if (lane == 0) smem[wave] = acc;
    __syncthreads();

    if (threadIdx.x == 0) {
        float s = 0.0f;
        #pragma unroll
        for (int w = 0; w < 4; ++w) s += smem[w];
        out[0] = s * (1.0f / (float)N_TOTAL);
    }
}

extern "C" void kernel_launch(void* const* d_in, const int* in_sizes, int n_in,
                              void* d_out, int out_size, void* d_ws, size_t ws_size,
                              hipStream_t stream) {
    const float* yp = (const float*)d_in[0];
    const float* yt = (const float*)d_in[1];
    float* out = (float*)d_out;
    float* partial = (float*)d_ws;   // BLOCKS floats = 4 KiB scratch

    svl_partial_kernel<<<BLOCKS, THREADS, 0, stream>>>(yp, yt, partial);
    svl_final_kernel<<<1, 256, 0, stream>>>(partial, out);
}